// Round 1
// 1399.771 us; speedup vs baseline: 1.4608x; 1.4608x over previous
//
#include <hip/hip_runtime.h>
#include <hip/hip_bf16.h>

#define BDIM 2
#define SDIM 4096
#define EDIM 2048
#define TOK (BDIM * SDIM)       // 8192
#define QK_SCALE 0.08838834764831845f  // 128^-0.5

typedef short bf16x8 __attribute__((ext_vector_type(8)));
typedef float f32x4 __attribute__((ext_vector_type(4)));

__device__ __forceinline__ unsigned short f2bf(float f) {
    unsigned u = __float_as_uint(f);
    u += 0x7FFF + ((u >> 16) & 1);          // RNE; inputs finite
    return (unsigned short)(u >> 16);
}

// fp32x8 -> bf16 hi + bf16 lo (residual), for near-fp32 MFMA via 3-term split
__device__ __forceinline__ void cvt_split8(const float4 a, const float4 b,
                                           bf16x8& hi, bf16x8& lo) {
    float f[8] = {a.x, a.y, a.z, a.w, b.x, b.y, b.z, b.w};
#pragma unroll
    for (int i = 0; i < 8; ++i) {
        const unsigned short h = f2bf(f[i]);
        hi[i] = (short)h;
        const float hf = __uint_as_float(((unsigned)h) << 16);
        lo[i] = (short)f2bf(f[i] - hf);
    }
}

// async 16B global -> LDS (wave-uniform base + lane*16 layout; LDS unpadded)
__device__ __forceinline__ void cp16(const void* g, void* l) {
    __builtin_amdgcn_global_load_lds(
        (const __attribute__((address_space(1))) unsigned int*)g,
        (__attribute__((address_space(3))) unsigned int*)l, 16, 0, 0);
}

// ---- one-time fp32 -> bf16 hi/lo split (hoisted out of the GEMMs) ----
__global__ __launch_bounds__(256) void split_kernel(
    const float* __restrict__ x,
    unsigned short* __restrict__ xh, unsigned short* __restrict__ xl) {
    const long i = ((long)blockIdx.x * 256 + threadIdx.x) * 8;
    const float4 f0 = *(const float4*)(x + i);
    const float4 f1 = *(const float4*)(x + i + 4);
    bf16x8 hi, lo;
    cvt_split8(f0, f1, hi, lo);
    *(bf16x8*)(xh + i) = hi;
    *(bf16x8*)(xl + i) = lo;
}

// ---------------- MFMA GEMM: C[m,n] = sum_k A[m,k] * B^T[n,k] ----------------
// A: M x K row-major, B: N x K row-major (B^T form). 128x128 tile, BK=32,
// 256 threads = 4 waves (2x2 of 64x64), mfma_f32_16x16x32_bf16.
// SA/SB: 0 = operand is bf16 in global (cp16 direct);
//        1 = operand is fp32 in global -> split into bf16 hi+lo tiles in-kernel;
//        2 = (SA only) operand pre-split: Ap = hi bf16, A2p = lo bf16, both
//            cp16-staged (no VALU cvt in the GEMM).
//        Product uses Ah*Bh + Ah*Bl + Al*Bh (near-fp32 precision).
// EPI: 0 = fp32 store to Cp;  1 = bf16 store to Cp;
//      2 = kv-split: n<2048 -> bf16 Cp (ldc), n>=2048 -> transposed bf16 Ct:
//          Ct[(batch*2048 + n-2048)*ldt + row_in_batch], batch = row>>12.
// C = (acc + bias[n]) * scale (bias fp32, nullable).
template <int SA, int SB, int EPI>
__global__ __launch_bounds__(256) void mfma_gemm(
    const void* __restrict__ Ap, const void* __restrict__ A2p, int lda,
    const void* __restrict__ Bp, int ldb,
    void* __restrict__ Cp, int ldc,
    unsigned short* __restrict__ Ct, int ldt,
    const float* __restrict__ bias, float scale, int K) {

    __shared__ short As[(SA ? 2 : 1) * 128 * 32];   // [+4096]: lo tile
    __shared__ short Bs[(SB ? 2 : 1) * 128 * 32];

    const int tid = threadIdx.x;
    const int m0 = blockIdx.y * 128;
    const int n0 = blockIdx.x * 128;

    const int lane = tid & 63;
    const int wave = tid >> 6;
    const int ln = lane & 15;
    const int quad = lane >> 4;
    const int wm = (wave >> 1) * 64;
    const int wn = (wave & 1) * 64;

    f32x4 acc[4][4] = {};

    const int srow = tid >> 2;          // 0..63 (+64 second pass)
    const int scol = (tid & 3) * 8;     // 0,8,16,24

    for (int kt = 0; kt < K; kt += 32) {
        if (kt) __syncthreads();

        // ---- stage A tile (128x32 bf16 [+lo]) ----
        if (SA == 1) {
#pragma unroll
            for (int p = 0; p < 2; ++p) {
                const int r = p * 64 + srow;
                const float* s = (const float*)Ap + (long)(m0 + r) * lda + kt + scol;
                const float4 f0 = *(const float4*)s;
                const float4 f1 = *(const float4*)(s + 4);
                bf16x8 hi, lo;
                cvt_split8(f0, f1, hi, lo);
                *(bf16x8*)&As[r * 32 + scol] = hi;
                *(bf16x8*)&As[4096 + r * 32 + scol] = lo;
            }
        } else if (SA == 2) {
#pragma unroll
            for (int p = 0; p < 2; ++p) {
                const int r = p * 64 + srow;
                const long off = (long)(m0 + r) * lda + kt + scol;
                cp16((const unsigned short*)Ap + off, &As[r * 32 + scol]);
                cp16((const unsigned short*)A2p + off, &As[4096 + r * 32 + scol]);
            }
        } else {
#pragma unroll
            for (int p = 0; p < 2; ++p) {
                const int r = p * 64 + srow;
                cp16((const unsigned short*)Ap + (long)(m0 + r) * lda + kt + scol,
                     &As[r * 32 + scol]);
            }
        }
        // ---- stage B tile (128x32 bf16 [+lo], B^T rows) ----
        if (SB) {
#pragma unroll
            for (int p = 0; p < 2; ++p) {
                const int r = p * 64 + srow;
                const float* s = (const float*)Bp + (long)(n0 + r) * ldb + kt + scol;
                const float4 f0 = *(const float4*)s;
                const float4 f1 = *(const float4*)(s + 4);
                bf16x8 hi, lo;
                cvt_split8(f0, f1, hi, lo);
                *(bf16x8*)&Bs[r * 32 + scol] = hi;
                *(bf16x8*)&Bs[4096 + r * 32 + scol] = lo;
            }
        } else {
#pragma unroll
            for (int p = 0; p < 2; ++p) {
                const int r = p * 64 + srow;
                cp16((const unsigned short*)Bp + (long)(n0 + r) * ldb + kt + scol,
                     &Bs[r * 32 + scol]);
            }
        }
        __syncthreads();   // drains vmcnt (global_load_lds) + lgkm (ds_write)

        // ---- fragments + MFMA ----
        bf16x8 ah[4], bh[4];
#pragma unroll
        for (int t = 0; t < 4; ++t)
            ah[t] = *(bf16x8*)&As[(wm + t * 16 + ln) * 32 + quad * 8];
#pragma unroll
        for (int t = 0; t < 4; ++t)
            bh[t] = *(bf16x8*)&Bs[(wn + t * 16 + ln) * 32 + quad * 8];

#pragma unroll
        for (int i = 0; i < 4; ++i)
#pragma unroll
            for (int j = 0; j < 4; ++j)
                acc[i][j] = __builtin_amdgcn_mfma_f32_16x16x32_bf16(
                    ah[i], bh[j], acc[i][j], 0, 0, 0);

        if (SB) {
            bf16x8 bl[4];
#pragma unroll
            for (int t = 0; t < 4; ++t)
                bl[t] = *(bf16x8*)&Bs[4096 + (wn + t * 16 + ln) * 32 + quad * 8];
#pragma unroll
            for (int i = 0; i < 4; ++i)
#pragma unroll
                for (int j = 0; j < 4; ++j)
                    acc[i][j] = __builtin_amdgcn_mfma_f32_16x16x32_bf16(
                        ah[i], bl[j], acc[i][j], 0, 0, 0);
        }
        if (SA) {
            bf16x8 al[4];
#pragma unroll
            for (int t = 0; t < 4; ++t)
                al[t] = *(bf16x8*)&As[4096 + (wm + t * 16 + ln) * 32 + quad * 8];
#pragma unroll
            for (int i = 0; i < 4; ++i)
#pragma unroll
                for (int j = 0; j < 4; ++j)
                    acc[i][j] = __builtin_amdgcn_mfma_f32_16x16x32_bf16(
                        al[i], bh[j], acc[i][j], 0, 0, 0);
        }
    }

    // ---- epilogue: C/D layout col=lane&15, row=quad*4+reg ----
#pragma unroll
    for (int i = 0; i < 4; ++i) {
        const int gm = m0 + wm + i * 16 + quad * 4;      // rows gm..gm+3
#pragma unroll
        for (int j = 0; j < 4; ++j) {
            const int gn = n0 + wn + j * 16 + ln;
            const float bv = bias ? bias[gn] : 0.0f;
            const f32x4 d = acc[i][j];
            if (EPI == 2 && gn >= 2048) {
                const int bt = gm >> 12;
                const int rl = gm & 4095;
                ushort4 t4;
                t4.x = f2bf((d[0] + bv) * scale);
                t4.y = f2bf((d[1] + bv) * scale);
                t4.z = f2bf((d[2] + bv) * scale);
                t4.w = f2bf((d[3] + bv) * scale);
                *(ushort4*)&Ct[((long)bt * 2048 + (gn - 2048)) * ldt + rl] = t4;
            } else if (EPI == 0) {
                float* Cf = (float*)Cp;
#pragma unroll
                for (int r = 0; r < 4; ++r)
                    Cf[(long)(gm + r) * ldc + gn] = (d[r] + bv) * scale;
            } else {
                unsigned short* Cb = (unsigned short*)Cp;
#pragma unroll
                for (int r = 0; r < 4; ++r)
                    Cb[(long)(gm + r) * ldc + gn] = f2bf((d[r] + bv) * scale);
            }
        }
    }
}

// ---------- RoPE in-place on bf16 (TOK x ld), ld cols = 16 heads x 128 ----------
__global__ __launch_bounds__(256) void rope_kernel(__hip_bfloat16* __restrict__ p, int ld) {
    const long idx = (long)blockIdx.x * 256 + threadIdx.x;  // < TOK*1024
    const int m = (int)(idx >> 10);
    const int r = (int)(idx & 1023);
    const int h = r >> 6;
    const int i = r & 63;
    const int s = m & (SDIM - 1);
    const float f = (float)s * expf(-(float)i * 0.14391156831212787f);
    float cs, sn;
    sincosf(f, &sn, &cs);
    __hip_bfloat16* b = p + (long)m * ld + h * 128 + i;
    const float x1 = __bfloat162float(b[0]);
    const float x2 = __bfloat162float(b[64]);
    b[0]  = __float2bfloat16(x1 * cs - x2 * sn);
    b[64] = __float2bfloat16(x2 * cs + x1 * sn);
}

// ---------- row softmax over 4096: read fp32, write bf16 in place ----------
__global__ __launch_bounds__(256) void softmax_kernel(float* __restrict__ S) {
    const long row = blockIdx.x;
    float* p = S + row * 4096;
    const int tid = threadIdx.x;
    const int lane = tid & 63;
    const int w = tid >> 6;
    __shared__ float red[4];

    float x[16];
#pragma unroll
    for (int i = 0; i < 4; ++i) {
        const float4 v = reinterpret_cast<const float4*>(p)[i * 256 + tid];
        x[i * 4 + 0] = v.x; x[i * 4 + 1] = v.y; x[i * 4 + 2] = v.z; x[i * 4 + 3] = v.w;
    }
    float m = -1e30f;
#pragma unroll
    for (int i = 0; i < 16; ++i) m = fmaxf(m, x[i]);
#pragma unroll
    for (int off = 1; off < 64; off <<= 1) m = fmaxf(m, __shfl_xor(m, off));
    if (lane == 0) red[w] = m;
    __syncthreads();
    const float M = fmaxf(fmaxf(red[0], red[1]), fmaxf(red[2], red[3]));
    __syncthreads();

    float s = 0.0f;
#pragma unroll
    for (int i = 0; i < 16; ++i) { x[i] = __expf(x[i] - M); s += x[i]; }
#pragma unroll
    for (int off = 1; off < 64; off <<= 1) s += __shfl_xor(s, off);
    if (lane == 0) red[w] = s;
    __syncthreads();                 // all reads done before in-place bf16 write
    const float inv = 1.0f / (red[0] + red[1] + red[2] + red[3]);

    ushort4* dst = (ushort4*)p;      // bf16 packed into first half of the row
#pragma unroll
    for (int i = 0; i < 4; ++i) {
        ushort4 t;
        t.x = f2bf(x[i * 4 + 0] * inv); t.y = f2bf(x[i * 4 + 1] * inv);
        t.z = f2bf(x[i * 4 + 2] * inv); t.w = f2bf(x[i * 4 + 3] * inv);
        dst[i * 256 + tid] = t;
    }
}

extern "C" void kernel_launch(void* const* d_in, const int* in_sizes, int n_in,
                              void* d_out, int out_size, void* d_ws, size_t ws_size,
                              hipStream_t stream) {
    const float* x    = (const float*)d_in[0];
    const float* q_w  = (const float*)d_in[1];
    const float* q_b  = (const float*)d_in[2];
    const float* kv_w = (const float*)d_in[3];
    const float* kv_b = (const float*)d_in[4];
    const float* o_w  = (const float*)d_in[5];
    float* out = (float*)d_out;

    // ws (96 MiB used, within proven 112):
    //   qo bf16 [8192 x 2048] 32MB | K bf16 [8192 x 2048] 32MB
    // | VT bf16 [2 x 2048 x 4096] 32MB
    // d_out (64 MiB) triple-duty scratch:
    //   phase 1: xh|xl bf16 hi/lo split of x (32MB+32MB)
    //   phase 2: per-batch fp32 scores [4096 x 4096] (64MB), softmax in place
    //   phase 3: final fp32 output (fully overwritten)
    unsigned short* qo = (unsigned short*)d_ws;
    unsigned short* kb = qo + (long)TOK * EDIM;
    unsigned short* vT = kb + (long)TOK * EDIM;
    unsigned short* xh = (unsigned short*)d_out;
    unsigned short* xl = xh + (long)TOK * EDIM;

    // 0) x -> xh + xl (bf16 hi/lo), once; removes per-block re-conversion
    split_kernel<<<(long)TOK * EDIM / 2048, 256, 0, stream>>>(x, xh, xl);

    // 1) q = (x @ q_w^T + q_b) * scale -> qo bf16   [A pre-split, B split: ~fp32]
    mfma_gemm<2, 1, 1><<<dim3(EDIM / 128, TOK / 128), 256, 0, stream>>>(
        xh, xl, EDIM, q_w, EDIM, qo, EDIM, nullptr, 0, q_b, QK_SCALE, EDIM);

    // 2) kv = x @ kv_w^T + kv_b -> K bf16 + VT bf16 transposed
    mfma_gemm<2, 1, 2><<<dim3(2 * EDIM / 128, TOK / 128), 256, 0, stream>>>(
        xh, xl, EDIM, kv_w, EDIM, kb, EDIM, vT, SDIM, kv_b, 1.0f, EDIM);

    // 3) RoPE on q and k
    rope_kernel<<<(long)TOK * 1024 / 256, 256, 0, stream>>>((__hip_bfloat16*)qo, EDIM);
    rope_kernel<<<(long)TOK * 1024 / 256, 256, 0, stream>>>((__hip_bfloat16*)kb, EDIM);

    // 4) per-batch attention (full 4096-row score buffer in d_out)
    for (int b = 0; b < BDIM; ++b) {
        float* scb = (float*)d_out;                    // 4096 x 4096 fp32
        const long ro = (long)b * SDIM * EDIM;

        // scores = q_b @ k_b^T  (fp32, full batch; 32x32 = 1024 blocks)
        mfma_gemm<0, 0, 0><<<dim3(SDIM / 128, SDIM / 128), 256, 0, stream>>>(
            qo + ro, nullptr, EDIM, kb + ro, EDIM,
            scb, SDIM, nullptr, 0, nullptr, 1.0f, EDIM);

        // softmax rows: fp32 -> bf16 in place (4096 rows, one launch)
        softmax_kernel<<<SDIM, 256, 0, stream>>>(scb);

        // o_b = P @ (VT)^T  (bf16 into qo rows; 16x32 = 512 blocks)
        mfma_gemm<0, 0, 1><<<dim3(EDIM / 128, SDIM / 128), 256, 0, stream>>>(
            (unsigned short*)scb, nullptr, 2 * SDIM,   // P bf16, row stride 8192
            vT + b * (long)EDIM * SDIM, SDIM,
            qo + ro, EDIM, nullptr, 0, nullptr, 1.0f, SDIM);
    }

    // 5) out = o @ o_w^T -> fp32 (overwrites all of d_out)   [o bf16, split o_w]
    mfma_gemm<0, 1, 0><<<dim3(EDIM / 128, TOK / 128), 256, 0, stream>>>(
        qo, nullptr, EDIM, o_w, EDIM, out, EDIM, nullptr, 0, nullptr, 1.0f, EDIM);
}

// Round 2
// 1359.468 us; speedup vs baseline: 1.5041x; 1.0296x over previous
//
#include <hip/hip_runtime.h>
#include <hip/hip_bf16.h>

#define BDIM 2
#define SDIM 4096
#define EDIM 2048
#define TOK (BDIM * SDIM)       // 8192
#define QK_SCALE 0.08838834764831845f  // 128^-0.5

typedef short bf16x8 __attribute__((ext_vector_type(8)));
typedef float f32x4 __attribute__((ext_vector_type(4)));

__device__ __forceinline__ unsigned short f2bf(float f) {
    unsigned u = __float_as_uint(f);
    u += 0x7FFF + ((u >> 16) & 1);          // RNE; inputs finite
    return (unsigned short)(u >> 16);
}

// fp32x8 -> bf16 hi + bf16 lo (residual), for near-fp32 MFMA via 3-term split
__device__ __forceinline__ void cvt_split8(const float4 a, const float4 b,
                                           bf16x8& hi, bf16x8& lo) {
    float f[8] = {a.x, a.y, a.z, a.w, b.x, b.y, b.z, b.w};
#pragma unroll
    for (int i = 0; i < 8; ++i) {
        const unsigned short h = f2bf(f[i]);
        hi[i] = (short)h;
        const float hf = __uint_as_float(((unsigned)h) << 16);
        lo[i] = (short)f2bf(f[i] - hf);
    }
}

// async 16B global -> LDS (wave-uniform base + lane*16 layout; LDS unpadded)
__device__ __forceinline__ void cp16(const void* g, void* l) {
    __builtin_amdgcn_global_load_lds(
        (const __attribute__((address_space(1))) unsigned int*)g,
        (__attribute__((address_space(3))) unsigned int*)l, 16, 0, 0);
}

// ---- one-time fp32 -> bf16 hi/lo split (hoisted out of the GEMMs) ----
// grid = nelems/2048, nelems multiple of 2048
__global__ __launch_bounds__(256) void split_kernel(
    const float* __restrict__ x,
    unsigned short* __restrict__ xh, unsigned short* __restrict__ xl) {
    const long i = ((long)blockIdx.x * 256 + threadIdx.x) * 8;
    const float4 f0 = *(const float4*)(x + i);
    const float4 f1 = *(const float4*)(x + i + 4);
    bf16x8 hi, lo;
    cvt_split8(f0, f1, hi, lo);
    *(bf16x8*)(xh + i) = hi;
    *(bf16x8*)(xl + i) = lo;
}

// ---------------- MFMA GEMM: C[m,n] = sum_k A[m,k] * B^T[n,k] ----------------
// A: M x K row-major, B: N x K row-major (B^T form). 128x128 tile, BK=32,
// 256 threads = 4 waves (2x2 of 64x64), mfma_f32_16x16x32_bf16.
// SA/SB: 0 = operand is bf16 in global (cp16 direct);
//        2 = operand pre-split: Xp = hi bf16, X2p = lo bf16, both cp16-staged
//            (zero VALU conversion in the GEMM).
//        Product uses Ah*Bh + Ah*Bl + Al*Bh (near-fp32 precision).
// EPI: 0 = fp32 store to Cp;  1 = bf16 store to Cp;
//      2 = kv-split: n<2048 -> bf16 Cp (ldc), n>=2048 -> transposed bf16 Ct:
//          Ct[(batch*2048 + n-2048)*ldt + row_in_batch], batch = row>>12.
// C = (acc + bias[n]) * scale (bias fp32, nullable).
template <int SA, int SB, int EPI>
__global__ __launch_bounds__(256) void mfma_gemm(
    const void* __restrict__ Ap, const void* __restrict__ A2p, int lda,
    const void* __restrict__ Bp, const void* __restrict__ B2p, int ldb,
    void* __restrict__ Cp, int ldc,
    unsigned short* __restrict__ Ct, int ldt,
    const float* __restrict__ bias, float scale, int K) {

    __shared__ short As[(SA ? 2 : 1) * 128 * 32];   // [+4096]: lo tile
    __shared__ short Bs[(SB ? 2 : 1) * 128 * 32];

    const int tid = threadIdx.x;
    const int m0 = blockIdx.y * 128;
    const int n0 = blockIdx.x * 128;

    const int lane = tid & 63;
    const int wave = tid >> 6;
    const int ln = lane & 15;
    const int quad = lane >> 4;
    const int wm = (wave >> 1) * 64;
    const int wn = (wave & 1) * 64;

    f32x4 acc[4][4] = {};

    const int srow = tid >> 2;          // 0..63 (+64 second pass)
    const int scol = (tid & 3) * 8;     // 0,8,16,24

    for (int kt = 0; kt < K; kt += 32) {
        if (kt) __syncthreads();

        // ---- stage A tile (128x32 bf16 [+lo]) ----
        if (SA == 2) {
#pragma unroll
            for (int p = 0; p < 2; ++p) {
                const int r = p * 64 + srow;
                const long off = (long)(m0 + r) * lda + kt + scol;
                cp16((const unsigned short*)Ap + off, &As[r * 32 + scol]);
                cp16((const unsigned short*)A2p + off, &As[4096 + r * 32 + scol]);
            }
        } else {
#pragma unroll
            for (int p = 0; p < 2; ++p) {
                const int r = p * 64 + srow;
                cp16((const unsigned short*)Ap + (long)(m0 + r) * lda + kt + scol,
                     &As[r * 32 + scol]);
            }
        }
        // ---- stage B tile (128x32 bf16 [+lo], B^T rows) ----
        if (SB == 2) {
#pragma unroll
            for (int p = 0; p < 2; ++p) {
                const int r = p * 64 + srow;
                const long off = (long)(n0 + r) * ldb + kt + scol;
                cp16((const unsigned short*)Bp + off, &Bs[r * 32 + scol]);
                cp16((const unsigned short*)B2p + off, &Bs[4096 + r * 32 + scol]);
            }
        } else {
#pragma unroll
            for (int p = 0; p < 2; ++p) {
                const int r = p * 64 + srow;
                cp16((const unsigned short*)Bp + (long)(n0 + r) * ldb + kt + scol,
                     &Bs[r * 32 + scol]);
            }
        }
        __syncthreads();   // drains vmcnt (global_load_lds)

        // ---- fragments + MFMA ----
        bf16x8 ah[4], bh[4];
#pragma unroll
        for (int t = 0; t < 4; ++t)
            ah[t] = *(bf16x8*)&As[(wm + t * 16 + ln) * 32 + quad * 8];
#pragma unroll
        for (int t = 0; t < 4; ++t)
            bh[t] = *(bf16x8*)&Bs[(wn + t * 16 + ln) * 32 + quad * 8];

#pragma unroll
        for (int i = 0; i < 4; ++i)
#pragma unroll
            for (int j = 0; j < 4; ++j)
                acc[i][j] = __builtin_amdgcn_mfma_f32_16x16x32_bf16(
                    ah[i], bh[j], acc[i][j], 0, 0, 0);

        if (SB) {
            bf16x8 bl[4];
#pragma unroll
            for (int t = 0; t < 4; ++t)
                bl[t] = *(bf16x8*)&Bs[4096 + (wn + t * 16 + ln) * 32 + quad * 8];
#pragma unroll
            for (int i = 0; i < 4; ++i)
#pragma unroll
                for (int j = 0; j < 4; ++j)
                    acc[i][j] = __builtin_amdgcn_mfma_f32_16x16x32_bf16(
                        ah[i], bl[j], acc[i][j], 0, 0, 0);
        }
        if (SA) {
            bf16x8 al[4];
#pragma unroll
            for (int t = 0; t < 4; ++t)
                al[t] = *(bf16x8*)&As[4096 + (wm + t * 16 + ln) * 32 + quad * 8];
#pragma unroll
            for (int i = 0; i < 4; ++i)
#pragma unroll
                for (int j = 0; j < 4; ++j)
                    acc[i][j] = __builtin_amdgcn_mfma_f32_16x16x32_bf16(
                        al[i], bh[j], acc[i][j], 0, 0, 0);
        }
    }

    // ---- epilogue: C/D layout col=lane&15, row=quad*4+reg ----
#pragma unroll
    for (int i = 0; i < 4; ++i) {
        const int gm = m0 + wm + i * 16 + quad * 4;      // rows gm..gm+3
#pragma unroll
        for (int j = 0; j < 4; ++j) {
            const int gn = n0 + wn + j * 16 + ln;
            const float bv = bias ? bias[gn] : 0.0f;
            const f32x4 d = acc[i][j];
            if (EPI == 2 && gn >= 2048) {
                const int bt = gm >> 12;
                const int rl = gm & 4095;
                ushort4 t4;
                t4.x = f2bf((d[0] + bv) * scale);
                t4.y = f2bf((d[1] + bv) * scale);
                t4.z = f2bf((d[2] + bv) * scale);
                t4.w = f2bf((d[3] + bv) * scale);
                *(ushort4*)&Ct[((long)bt * 2048 + (gn - 2048)) * ldt + rl] = t4;
            } else if (EPI == 0) {
                float* Cf = (float*)Cp;
#pragma unroll
                for (int r = 0; r < 4; ++r)
                    Cf[(long)(gm + r) * ldc + gn] = (d[r] + bv) * scale;
            } else {
                unsigned short* Cb = (unsigned short*)Cp;
#pragma unroll
                for (int r = 0; r < 4; ++r)
                    Cb[(long)(gm + r) * ldc + gn] = f2bf((d[r] + bv) * scale);
            }
        }
    }
}

// ---------- RoPE in-place on bf16 (TOK x ld), ld cols = 16 heads x 128 ----------
__global__ __launch_bounds__(256) void rope_kernel(__hip_bfloat16* __restrict__ p, int ld) {
    const long idx = (long)blockIdx.x * 256 + threadIdx.x;  // < TOK*1024
    const int m = (int)(idx >> 10);
    const int r = (int)(idx & 1023);
    const int h = r >> 6;
    const int i = r & 63;
    const int s = m & (SDIM - 1);
    const float f = (float)s * expf(-(float)i * 0.14391156831212787f);
    float cs, sn;
    sincosf(f, &sn, &cs);
    __hip_bfloat16* b = p + (long)m * ld + h * 128 + i;
    const float x1 = __bfloat162float(b[0]);
    const float x2 = __bfloat162float(b[64]);
    b[0]  = __float2bfloat16(x1 * cs - x2 * sn);
    b[64] = __float2bfloat16(x2 * cs + x1 * sn);
}

// ---------- row softmax over 4096: read fp32, write bf16 in place ----------
__global__ __launch_bounds__(256) void softmax_kernel(float* __restrict__ S) {
    const long row = blockIdx.x;
    float* p = S + row * 4096;
    const int tid = threadIdx.x;
    const int lane = tid & 63;
    const int w = tid >> 6;
    __shared__ float red[4];

    float x[16];
#pragma unroll
    for (int i = 0; i < 4; ++i) {
        const float4 v = reinterpret_cast<const float4*>(p)[i * 256 + tid];
        x[i * 4 + 0] = v.x; x[i * 4 + 1] = v.y; x[i * 4 + 2] = v.z; x[i * 4 + 3] = v.w;
    }
    float m = -1e30f;
#pragma unroll
    for (int i = 0; i < 16; ++i) m = fmaxf(m, x[i]);
#pragma unroll
    for (int off = 1; off < 64; off <<= 1) m = fmaxf(m, __shfl_xor(m, off));
    if (lane == 0) red[w] = m;
    __syncthreads();
    const float M = fmaxf(fmaxf(red[0], red[1]), fmaxf(red[2], red[3]));
    __syncthreads();

    float s = 0.0f;
#pragma unroll
    for (int i = 0; i < 16; ++i) { x[i] = __expf(x[i] - M); s += x[i]; }
#pragma unroll
    for (int off = 1; off < 64; off <<= 1) s += __shfl_xor(s, off);
    if (lane == 0) red[w] = s;
    __syncthreads();                 // all reads done before in-place bf16 write
    const float inv = 1.0f / (red[0] + red[1] + red[2] + red[3]);

    ushort4* dst = (ushort4*)p;      // bf16 packed into first half of the row
#pragma unroll
    for (int i = 0; i < 4; ++i) {
        ushort4 t;
        t.x = f2bf(x[i * 4 + 0] * inv); t.y = f2bf(x[i * 4 + 1] * inv);
        t.z = f2bf(x[i * 4 + 2] * inv); t.w = f2bf(x[i * 4 + 3] * inv);
        dst[i * 256 + tid] = t;
    }
}

extern "C" void kernel_launch(void* const* d_in, const int* in_sizes, int n_in,
                              void* d_out, int out_size, void* d_ws, size_t ws_size,
                              hipStream_t stream) {
    const float* x    = (const float*)d_in[0];
    const float* q_w  = (const float*)d_in[1];
    const float* q_b  = (const float*)d_in[2];
    const float* kv_w = (const float*)d_in[3];
    const float* kv_b = (const float*)d_in[4];
    const float* o_w  = (const float*)d_in[5];
    float* out = (float*)d_out;

    // ws (112 MiB, proven mapped), time-multiplexed:
    //   [0..32M)   qo slot: phase A = kv_w hi/lo split (16+16MB); phase B+ = q/o bf16
    //   [32..64M)  kb slot: K bf16; after attention reused for o_w hi/lo (16MB)
    //   [64..96M)  vT bf16 [2 x 2048 x 4096]
    //   [96..112M) q_w hi/lo split (8+8MB)
    // d_out (64 MiB) triple-duty:
    //   phase 1: xh|xl bf16 hi/lo split of x (32+32MB)
    //   phase 2: per-batch fp32 scores [4096 x 4096] (64MB), softmax in place
    //   phase 3: final fp32 output (fully overwritten)
    unsigned short* qo  = (unsigned short*)d_ws;
    unsigned short* kb  = qo + (long)TOK * EDIM;
    unsigned short* vT  = kb + (long)TOK * EDIM;
    unsigned short* qwh = vT + (long)BDIM * EDIM * SDIM;   // 96MB offset
    unsigned short* qwl = qwh + (long)EDIM * EDIM;
    unsigned short* kvh = qo;                               // aliases qo slot
    unsigned short* kvl = kvh + (long)2 * EDIM * EDIM;
    unsigned short* owh = kb;                               // aliases kb slot
    unsigned short* owl = owh + (long)EDIM * EDIM;
    unsigned short* xh  = (unsigned short*)d_out;
    unsigned short* xl  = xh + (long)TOK * EDIM;

    // 0) one-time hi/lo splits (removes ALL in-GEMM fp32->bf16 conversion)
    split_kernel<<<(long)TOK * EDIM / 2048, 256, 0, stream>>>(x, xh, xl);
    split_kernel<<<(long)2 * EDIM * EDIM / 2048, 256, 0, stream>>>(kv_w, kvh, kvl);

    // 1) kv = x @ kv_w^T + kv_b -> K bf16 + VT bf16 transposed
    //    (runs BEFORE q-proj so kv_w split can live in the qo slot)
    mfma_gemm<2, 2, 2><<<dim3(2 * EDIM / 128, TOK / 128), 256, 0, stream>>>(
        xh, xl, EDIM, kvh, kvl, EDIM, kb, EDIM, vT, SDIM, kv_b, 1.0f, EDIM);

    // 2) q = (x @ q_w^T + q_b) * scale -> qo bf16 (overwrites consumed kv split)
    split_kernel<<<(long)EDIM * EDIM / 2048, 256, 0, stream>>>(q_w, qwh, qwl);
    mfma_gemm<2, 2, 1><<<dim3(EDIM / 128, TOK / 128), 256, 0, stream>>>(
        xh, xl, EDIM, qwh, qwl, EDIM, qo, EDIM, nullptr, 0, q_b, QK_SCALE, EDIM);

    // 3) RoPE on q and k
    rope_kernel<<<(long)TOK * 1024 / 256, 256, 0, stream>>>((__hip_bfloat16*)qo, EDIM);
    rope_kernel<<<(long)TOK * 1024 / 256, 256, 0, stream>>>((__hip_bfloat16*)kb, EDIM);

    // 4) per-batch attention (full 4096-row score buffer in d_out; xh/xl dead)
    for (int b = 0; b < BDIM; ++b) {
        float* scb = (float*)d_out;                    // 4096 x 4096 fp32
        const long ro = (long)b * SDIM * EDIM;

        // scores = q_b @ k_b^T  (fp32, full batch; 32x32 = 1024 blocks)
        mfma_gemm<0, 0, 0><<<dim3(SDIM / 128, SDIM / 128), 256, 0, stream>>>(
            qo + ro, nullptr, EDIM, kb + ro, nullptr, EDIM,
            scb, SDIM, nullptr, 0, nullptr, 1.0f, EDIM);

        // softmax rows: fp32 -> bf16 in place (4096 rows, one launch)
        softmax_kernel<<<SDIM, 256, 0, stream>>>(scb);

        // o_b = P @ (VT)^T  (bf16 into qo rows; 16x32 = 512 blocks)
        mfma_gemm<0, 0, 1><<<dim3(EDIM / 128, SDIM / 128), 256, 0, stream>>>(
            (unsigned short*)scb, nullptr, 2 * SDIM,   // P bf16, row stride 8192
            vT + b * (long)EDIM * SDIM, nullptr, SDIM,
            qo + ro, EDIM, nullptr, 0, nullptr, 1.0f, SDIM);
    }

    // 5) out = o @ o_w^T -> fp32 (overwrites all of d_out; kb slot dead -> o_w split)
    split_kernel<<<(long)EDIM * EDIM / 2048, 256, 0, stream>>>(o_w, owh, owl);
    mfma_gemm<0, 2, 0><<<dim3(EDIM / 128, TOK / 128), 256, 0, stream>>>(
        qo, nullptr, EDIM, owh, owl, EDIM, out, EDIM, nullptr, 0, nullptr, 1.0f, EDIM);
}